// Round 1
// baseline (282.531 us; speedup 1.0000x reference)
//
#include <hip/hip_runtime.h>
#include <stdint.h>

// MoE: D=1024, N=8 experts, top-1 routed (experts 0..6) + shared expert 7,
// all gates are exactly 1.0 (see softmax/renorm collapse in the reference).
// M = B*S = 2048 tokens, H = 2048, W1 per expert [1024][4096], W2 [2048][1024].

typedef __bf16 bf16x8 __attribute__((ext_vector_type(8)));
typedef float f32x4 __attribute__((ext_vector_type(4)));

typedef __attribute__((address_space(1))) const void gvoid_t;
typedef __attribute__((address_space(3))) void lvoid_t;

__device__ __forceinline__ void gload16(void* lds, const void* g) {
  __builtin_amdgcn_global_load_lds((gvoid_t*)g, (lvoid_t*)lds, 16, 0, 0);
}

__device__ __forceinline__ uint16_t f2bf(float f) {
  union { float f; uint32_t u; } v; v.f = f;
  uint32_t u = v.u + 0x7fffu + ((v.u >> 16) & 1u);  // RNE
  return (uint16_t)(u >> 16);
}

// ---------------- fp32 -> bf16 straight convert (for x) ----------------
__global__ __launch_bounds__(256) void cvt_kernel(const float* __restrict__ src,
                                                  uint16_t* __restrict__ dst, int n4) {
  int i = blockIdx.x * blockDim.x + threadIdx.x;
  if (i >= n4) return;
  float4 v = reinterpret_cast<const float4*>(src)[i];
  ushort4 o;
  o.x = f2bf(v.x); o.y = f2bf(v.y); o.z = f2bf(v.z); o.w = f2bf(v.w);
  reinterpret_cast<ushort4*>(dst)[i] = o;
}

// ------- per-expert transpose+convert: src [E][R][C] f32 -> dst [E][C][R] bf16 -------
__global__ __launch_bounds__(256) void tcvt_kernel(const float* __restrict__ src,
                                                   uint16_t* __restrict__ dst,
                                                   int R, int C) {
  __shared__ uint16_t tile[64][80];  // 80: keep 16B alignment of [cl][rg*8], break conflicts
  int e = blockIdx.z;
  const float* s = src + (size_t)e * R * C;
  uint16_t* d = dst + (size_t)e * R * C;
  int c0 = blockIdx.x * 64, r0 = blockIdx.y * 64;
  int t = threadIdx.x;
  int rl = t >> 4, cq = t & 15;
  for (int it = 0; it < 4; ++it) {
    int r = rl + it * 16;
    float4 v = *reinterpret_cast<const float4*>(s + (size_t)(r0 + r) * C + c0 + cq * 4);
    tile[cq * 4 + 0][r] = f2bf(v.x);
    tile[cq * 4 + 1][r] = f2bf(v.y);
    tile[cq * 4 + 2][r] = f2bf(v.z);
    tile[cq * 4 + 3][r] = f2bf(v.w);
  }
  __syncthreads();
  for (int it = 0; it < 2; ++it) {
    int slot = t + it * 256;
    int cl = slot >> 3, rg = slot & 7;
    uint4 v = *reinterpret_cast<const uint4*>(&tile[cl][rg * 8]);
    *reinterpret_cast<uint4*>(d + (size_t)(c0 + cl) * R + r0 + rg * 8) = v;
  }
}

// ---------------- gating: scores, argmax over experts 0..6 ----------------
__global__ __launch_bounds__(256) void gate_kernel(const float* __restrict__ x,
                                                   const float* __restrict__ Wg,
                                                   int* __restrict__ idx,
                                                   int* __restrict__ perm,
                                                   int* __restrict__ cnt) {
  int wid = threadIdx.x >> 6, lane = threadIdx.x & 63;
  int m = blockIdx.x * 4 + wid;
  const float* xr = x + (size_t)m * 1024;
  float acc[8] = {0.f, 0.f, 0.f, 0.f, 0.f, 0.f, 0.f, 0.f};
  for (int it = 0; it < 4; ++it) {
    int dbase = it * 256 + lane * 4;
    float4 xv = *reinterpret_cast<const float4*>(xr + dbase);
    const float* xp = reinterpret_cast<const float*>(&xv);
    for (int dd = 0; dd < 4; ++dd) {
      float xs = xp[dd];
      float4 w0 = *reinterpret_cast<const float4*>(Wg + (size_t)(dbase + dd) * 8);
      float4 w1 = *reinterpret_cast<const float4*>(Wg + (size_t)(dbase + dd) * 8 + 4);
      acc[0] += xs * w0.x; acc[1] += xs * w0.y; acc[2] += xs * w0.z; acc[3] += xs * w0.w;
      acc[4] += xs * w1.x; acc[5] += xs * w1.y; acc[6] += xs * w1.z; acc[7] += xs * w1.w;
    }
  }
  for (int j = 0; j < 8; ++j)
    for (int off = 32; off; off >>= 1)
      acc[j] += __shfl_xor(acc[j], off);
  if (lane == 0) {
    int best = 0; float bv = acc[0];
    for (int j = 1; j < 7; ++j) if (acc[j] > bv) { bv = acc[j]; best = j; }
    idx[m] = best;
    perm[m] = atomicAdd(cnt + best, 1);
  }
}

// ---------------- build segment offsets + rowmap ----------------
__global__ void compact_kernel(const int* __restrict__ idx, const int* __restrict__ perm,
                               const int* __restrict__ cnt, int* __restrict__ soff,
                               int* __restrict__ scnt, int* __restrict__ rowmap) {
  __shared__ int offs[8];
  if (threadIdx.x == 0) {
    int run = 0;
    for (int e = 0; e < 7; ++e) { soff[e] = run; scnt[e] = cnt[e]; offs[e] = run; run += cnt[e]; }
    soff[7] = 2048; scnt[7] = 2048;
  }
  __syncthreads();
  for (int m = threadIdx.x; m < 2048; m += blockDim.x) {
    rowmap[offs[idx[m]] + perm[m]] = m;  // routed compact rows [0,2048)
    rowmap[2048 + m] = m;                // shared identity rows [2048,4096)
  }
}

// ---------------- FFN1: h = silu(x@W1_b) * (x@W1_a), gathered rows ----------------
// grid (32 h-coltiles of 64, 16 rowtiles of 128, 8 segments), 256 threads (4 waves, 2x2)
__global__ __launch_bounds__(256) void ffn1_kernel(
    const uint16_t* __restrict__ xbf,   // [2048][1024] bf16
    const uint16_t* __restrict__ w1t,   // [8][4096][1024] bf16 (transposed: [n][d])
    const int* __restrict__ soff, const int* __restrict__ scnt,
    const int* __restrict__ rowmap,
    uint16_t* __restrict__ h)           // [4096][2048] bf16
{
  int seg = blockIdx.z;
  int cnt = scnt[seg];
  int rt = blockIdx.y;
  if (rt * 128 >= cnt) return;
  int base = soff[seg];
  int n0 = blockIdx.x * 64;

  __shared__ uint16_t As[128 * 64];
  __shared__ uint16_t Ba[64 * 64];
  __shared__ uint16_t Bb[64 * 64];

  int lane = threadIdx.x & 63, wid = threadIdx.x >> 6;
  int wr = wid >> 1, wc = wid & 1;
  int cg = lane & 7;

  const uint16_t* w1e = w1t + (size_t)seg * (4096u * 1024u);

  const uint16_t* asrc[4];
  for (int i = 0; i < 4; ++i) {
    int row = wid * 32 + i * 8 + (lane >> 3);
    int rr = rt * 128 + row;
    if (rr >= cnt) rr = cnt - 1;  // clamp; stores masked later
    asrc[i] = xbf + (size_t)rowmap[base + rr] * 1024 + cg * 8;
  }
  const uint16_t* basrc[2];
  const uint16_t* bbsrc[2];
  for (int i = 0; i < 2; ++i) {
    int n = wid * 16 + i * 8 + (lane >> 3);
    basrc[i] = w1e + (size_t)(n0 + n) * 1024 + cg * 8;
    bbsrc[i] = w1e + (size_t)(2048 + n0 + n) * 1024 + cg * 8;
  }

  f32x4 acca[4][2] = {};
  f32x4 accb[4][2] = {};

  for (int k0 = 0; k0 < 1024; k0 += 64) {
    for (int i = 0; i < 4; ++i) gload16(&As[(wid * 4 + i) * 512], asrc[i] + k0);
    for (int i = 0; i < 2; ++i) gload16(&Ba[(wid * 2 + i) * 512], basrc[i] + k0);
    for (int i = 0; i < 2; ++i) gload16(&Bb[(wid * 2 + i) * 512], bbsrc[i] + k0);
    __syncthreads();
    for (int kk = 0; kk < 64; kk += 32) {
      int klo = kk + ((lane >> 4) << 3);
      bf16x8 af[4];
      for (int m = 0; m < 4; ++m) {
        int row = wr * 64 + m * 16 + (lane & 15);
        af[m] = *reinterpret_cast<const bf16x8*>(&As[row * 64 + klo]);
      }
      for (int n = 0; n < 2; ++n) {
        int col = wc * 32 + n * 16 + (lane & 15);
        bf16x8 ba = *reinterpret_cast<const bf16x8*>(&Ba[col * 64 + klo]);
        bf16x8 bb = *reinterpret_cast<const bf16x8*>(&Bb[col * 64 + klo]);
        for (int m = 0; m < 4; ++m) {
          acca[m][n] = __builtin_amdgcn_mfma_f32_16x16x32_bf16(af[m], ba, acca[m][n], 0, 0, 0);
          accb[m][n] = __builtin_amdgcn_mfma_f32_16x16x32_bf16(af[m], bb, accb[m][n], 0, 0, 0);
        }
      }
    }
    __syncthreads();
  }

  for (int m = 0; m < 4; ++m) {
    int rbase = rt * 128 + wr * 64 + m * 16 + ((lane >> 4) << 2);
    for (int n = 0; n < 2; ++n) {
      int col = n0 + wc * 32 + n * 16 + (lane & 15);
      for (int j = 0; j < 4; ++j) {
        int rr = rbase + j;
        if (rr < cnt) {
          float a = acca[m][n][j], b = accb[m][n][j];
          float sv = b / (1.0f + __expf(-b));  // silu
          h[(size_t)(base + rr) * 2048 + col] = f2bf(sv * a);
        }
      }
    }
  }
}

// ---------------- FFN2: y[token] (+)= h @ W2 ----------------
// grid (16 y-coltiles of 64, 16 rowtiles of 128, nseg), 256 threads
template <int ADD>
__global__ __launch_bounds__(256) void ffn2_kernel(
    const uint16_t* __restrict__ h,    // [4096][2048] bf16
    const uint16_t* __restrict__ w2t,  // [8][1024][2048] bf16 (transposed: [dout][h])
    const int* __restrict__ soff, const int* __restrict__ scnt,
    const int* __restrict__ rowmap, float* __restrict__ y, int seg0)
{
  int seg = seg0 + blockIdx.z;
  int cnt = scnt[seg];
  int rt = blockIdx.y;
  if (rt * 128 >= cnt) return;
  int base = soff[seg];
  int n0 = blockIdx.x * 64;

  __shared__ uint16_t As[128 * 64];
  __shared__ uint16_t Bs[64 * 64];

  int lane = threadIdx.x & 63, wid = threadIdx.x >> 6;
  int wr = wid >> 1, wc = wid & 1;
  int cg = lane & 7;

  const uint16_t* w2e = w2t + (size_t)seg * (1024u * 2048u);

  const uint16_t* asrc[4];
  for (int i = 0; i < 4; ++i) {
    int row = wid * 32 + i * 8 + (lane >> 3);
    int rr = rt * 128 + row;
    if (rr >= cnt) rr = cnt - 1;
    asrc[i] = h + (size_t)(base + rr) * 2048 + cg * 8;
  }
  const uint16_t* bsrc[2];
  for (int i = 0; i < 2; ++i) {
    int n = wid * 16 + i * 8 + (lane >> 3);
    bsrc[i] = w2e + (size_t)(n0 + n) * 2048 + cg * 8;
  }

  f32x4 acc[4][2] = {};

  for (int k0 = 0; k0 < 2048; k0 += 64) {
    for (int i = 0; i < 4; ++i) gload16(&As[(wid * 4 + i) * 512], asrc[i] + k0);
    for (int i = 0; i < 2; ++i) gload16(&Bs[(wid * 2 + i) * 512], bsrc[i] + k0);
    __syncthreads();
    for (int kk = 0; kk < 64; kk += 32) {
      int klo = kk + ((lane >> 4) << 3);
      bf16x8 af[4];
      for (int m = 0; m < 4; ++m)
        af[m] = *reinterpret_cast<const bf16x8*>(&As[(wr * 64 + m * 16 + (lane & 15)) * 64 + klo]);
      for (int n = 0; n < 2; ++n) {
        bf16x8 bfr = *reinterpret_cast<const bf16x8*>(&Bs[(wc * 32 + n * 16 + (lane & 15)) * 64 + klo]);
        for (int m = 0; m < 4; ++m)
          acc[m][n] = __builtin_amdgcn_mfma_f32_16x16x32_bf16(af[m], bfr, acc[m][n], 0, 0, 0);
      }
    }
    __syncthreads();
  }

  for (int m = 0; m < 4; ++m) {
    int rbase = rt * 128 + wr * 64 + m * 16 + ((lane >> 4) << 2);
    for (int n = 0; n < 2; ++n) {
      int col = n0 + wc * 32 + n * 16 + (lane & 15);
      for (int j = 0; j < 4; ++j) {
        int rr = rbase + j;
        if (rr < cnt) {
          int tok = rowmap[base + rr];
          if (ADD) y[(size_t)tok * 1024 + col] += acc[m][n][j];
          else     y[(size_t)tok * 1024 + col]  = acc[m][n][j];
        }
      }
    }
  }
}

extern "C" void kernel_launch(void* const* d_in, const int* in_sizes, int n_in,
                              void* d_out, int out_size, void* d_ws, size_t ws_size,
                              hipStream_t stream)
{
  const float* x   = (const float*)d_in[0];   // [2048][1024]
  const float* Wg  = (const float*)d_in[1];   // [1024][8]
  const float* Wl1 = (const float*)d_in[2];   // [8][1024][4096]
  const float* Wl2 = (const float*)d_in[3];   // [8][2048][1024]
  float* y = (float*)d_out;                   // [2048][1024]
  char* ws = (char*)d_ws;

  // ws layout (116 MiB + ~28 KiB of ints)
  uint16_t* xbf = (uint16_t*)(ws);                    //  4 MiB  [2048][1024]
  uint16_t* w1t = (uint16_t*)(ws + (4ull  << 20));    // 64 MiB  [8][4096][1024]
  uint16_t* w2t = (uint16_t*)(ws + (68ull << 20));    // 32 MiB  [8][1024][2048]
  uint16_t* h   = (uint16_t*)(ws + (100ull << 20));   // 16 MiB  [4096][2048]
  int* idx    = (int*)(ws + (116ull << 20));
  int* perm   = idx + 2048;
  int* cnt    = perm + 2048;
  int* soff   = cnt + 8;
  int* scnt   = soff + 8;
  int* rowmap = scnt + 8;  // 4096 ints

  hipMemsetAsync(cnt, 0, 8 * sizeof(int), stream);
  cvt_kernel<<<2048, 256, 0, stream>>>(x, xbf, 2048 * 1024 / 4);
  tcvt_kernel<<<dim3(64, 16, 8), 256, 0, stream>>>(Wl1, w1t, 1024, 4096);
  tcvt_kernel<<<dim3(16, 32, 8), 256, 0, stream>>>(Wl2, w2t, 2048, 1024);
  gate_kernel<<<512, 256, 0, stream>>>(x, Wg, idx, perm, cnt);
  compact_kernel<<<1, 256, 0, stream>>>(idx, perm, cnt, soff, scnt, rowmap);
  ffn1_kernel<<<dim3(32, 16, 8), 256, 0, stream>>>(xbf, w1t, soff, scnt, rowmap, h);
  ffn2_kernel<0><<<dim3(16, 16, 1), 256, 0, stream>>>(h, w2t, soff, scnt, rowmap, y, 7);
  ffn2_kernel<1><<<dim3(16, 16, 7), 256, 0, stream>>>(h, w2t, soff, scnt, rowmap, y, 0);
}

// Round 2
// 186.671 us; speedup vs baseline: 1.5135x; 1.5135x over previous
//
#include <hip/hip_runtime.h>
#include <stdint.h>

// MoE: D=1024, N=8 experts, top-1 routed (experts 0..6) + shared expert 7,
// gates are exactly 1.0. M=2048 tokens, H=2048.

typedef __bf16 bf16x8 __attribute__((ext_vector_type(8)));
typedef float f32x4 __attribute__((ext_vector_type(4)));

typedef __attribute__((address_space(1))) const void gvoid_t;
typedef __attribute__((address_space(3))) void lvoid_t;

__device__ __forceinline__ void gload16(void* lds, const void* g) {
  __builtin_amdgcn_global_load_lds((gvoid_t*)g, (lvoid_t*)lds, 16, 0, 0);
}

__device__ __forceinline__ uint16_t f2bf(float f) {
  union { float f; uint32_t u; } v; v.f = f;
  uint32_t u = v.u + 0x7fffu + ((v.u >> 16) & 1u);  // RNE
  return (uint16_t)(u >> 16);
}

#define S_VMCNT8() asm volatile("s_waitcnt vmcnt(8)" ::: "memory")
#define S_VMCNT0() asm volatile("s_waitcnt vmcnt(0)" ::: "memory")
#define S_LGKM0()  asm volatile("s_waitcnt lgkmcnt(0)" ::: "memory")
#define S_BAR()    __builtin_amdgcn_s_barrier()

// ------- per-expert transpose+convert: src [E][R][C] f32 -> dst [E][C][R] bf16 -------
__global__ __launch_bounds__(256) void tcvt_kernel(const float* __restrict__ src,
                                                   uint16_t* __restrict__ dst,
                                                   int R, int C) {
  __shared__ uint16_t tile[64][80];
  int e = blockIdx.z;
  const float* s = src + (size_t)e * R * C;
  uint16_t* d = dst + (size_t)e * R * C;
  int c0 = blockIdx.x * 64, r0 = blockIdx.y * 64;
  int t = threadIdx.x;
  int rl = t >> 4, cq = t & 15;
  for (int it = 0; it < 4; ++it) {
    int r = rl + it * 16;
    float4 v = *reinterpret_cast<const float4*>(s + (size_t)(r0 + r) * C + c0 + cq * 4);
    tile[cq * 4 + 0][r] = f2bf(v.x);
    tile[cq * 4 + 1][r] = f2bf(v.y);
    tile[cq * 4 + 2][r] = f2bf(v.z);
    tile[cq * 4 + 3][r] = f2bf(v.w);
  }
  __syncthreads();
  for (int it = 0; it < 2; ++it) {
    int slot = t + it * 256;
    int cl = slot >> 3, rg = slot & 7;
    uint4 v = *reinterpret_cast<const uint4*>(&tile[cl][rg * 8]);
    *reinterpret_cast<uint4*>(d + (size_t)(c0 + cl) * R + r0 + rg * 8) = v;
  }
}

// ---------------- gating + x->bf16 convert fused ----------------
__global__ __launch_bounds__(256) void gate_kernel(const float* __restrict__ x,
                                                   const float* __restrict__ Wg,
                                                   uint16_t* __restrict__ xbf,
                                                   int* __restrict__ idx,
                                                   int* __restrict__ perm,
                                                   int* __restrict__ cnt) {
  int wid = threadIdx.x >> 6, lane = threadIdx.x & 63;
  int m = blockIdx.x * 4 + wid;
  const float* xr = x + (size_t)m * 1024;
  uint16_t* xbr = xbf + (size_t)m * 1024;
  float acc[8] = {0.f, 0.f, 0.f, 0.f, 0.f, 0.f, 0.f, 0.f};
  for (int it = 0; it < 4; ++it) {
    int dbase = it * 256 + lane * 4;
    float4 xv = *reinterpret_cast<const float4*>(xr + dbase);
    ushort4 o;
    o.x = f2bf(xv.x); o.y = f2bf(xv.y); o.z = f2bf(xv.z); o.w = f2bf(xv.w);
    *reinterpret_cast<ushort4*>(xbr + dbase) = o;
    const float* xp = reinterpret_cast<const float*>(&xv);
    for (int dd = 0; dd < 4; ++dd) {
      float xs = xp[dd];
      float4 w0 = *reinterpret_cast<const float4*>(Wg + (size_t)(dbase + dd) * 8);
      float4 w1 = *reinterpret_cast<const float4*>(Wg + (size_t)(dbase + dd) * 8 + 4);
      acc[0] += xs * w0.x; acc[1] += xs * w0.y; acc[2] += xs * w0.z; acc[3] += xs * w0.w;
      acc[4] += xs * w1.x; acc[5] += xs * w1.y; acc[6] += xs * w1.z; acc[7] += xs * w1.w;
    }
  }
  for (int j = 0; j < 7; ++j)
    for (int off = 32; off; off >>= 1)
      acc[j] += __shfl_xor(acc[j], off);
  if (lane == 0) {
    int best = 0; float bv = acc[0];
    for (int j = 1; j < 7; ++j) if (acc[j] > bv) { bv = acc[j]; best = j; }
    idx[m] = best;
    perm[m] = atomicAdd(cnt + best, 1);
  }
}

// ---------------- segment offsets + rowmap + token->routed-row map ----------------
__global__ void compact_kernel(const int* __restrict__ idx, const int* __restrict__ perm,
                               const int* __restrict__ cnt, int* __restrict__ soff,
                               int* __restrict__ scnt, int* __restrict__ rowmap,
                               int* __restrict__ tokrow) {
  __shared__ int offs[8];
  if (threadIdx.x == 0) {
    int run = 0;
    for (int e = 0; e < 7; ++e) { soff[e] = run; scnt[e] = cnt[e]; offs[e] = run; run += cnt[e]; }
    soff[7] = 0; scnt[7] = 2048;
  }
  __syncthreads();
  for (int m = threadIdx.x; m < 2048; m += blockDim.x) {
    int r = offs[idx[m]] + perm[m];
    rowmap[r] = m;
    tokrow[m] = r;
  }
}

// ---------------- FFN1: h = silu(x@W1_b) * (x@W1_a) ----------------
// BM=128 rows, 64 a-cols + 64 b-cols, BK=64, dbuf counted-vmcnt, swizzled LDS.
// grid (32 coltiles, 58 y-tiles), 256 threads (4 waves 2x2). LDS 64KB -> 2 blocks/CU.
__global__ __launch_bounds__(256, 2) void ffn1_kernel(
    const uint16_t* __restrict__ xbf,   // [2048][1024] bf16
    const uint16_t* __restrict__ w1t,   // [8][4096][1024] bf16 ([n][d])
    const int* __restrict__ soff, const int* __restrict__ scnt,
    const int* __restrict__ rowmap,
    uint16_t* __restrict__ h)           // [4096 compact rows][2048] bf16
{
  int by = blockIdx.y;
  int seg, rt;
  if (by < 42) { seg = by / 6; rt = by % 6; } else { seg = 7; rt = by - 42; }
  int cnt = scnt[seg];
  if (rt * 128 >= cnt) return;
  int base = (seg == 7) ? 2048 : soff[seg];   // h rows: routed [0,2048), shared [2048,4096)
  int rbase = (seg == 7) ? 0 : soff[seg];     // rowmap base (shared = identity)
  int n0 = blockIdx.x * 64;

  __shared__ uint16_t lds[2][16384];  // per buf: As[128][64]@0, Ba[64][64]@8192, Bb@12288

  int t = threadIdx.x, lane = t & 63, w = t >> 6;
  int trow = w * 8 + ((t >> 3) & 7);          // 0..31
  int slot = (t & 7) ^ (trow & 7);            // inverse-swizzled 16B slot

  const uint16_t* w1e = w1t + (size_t)seg * (4096u * 1024u);
  const uint16_t* aptr[4];
#pragma unroll
  for (int i = 0; i < 4; ++i) {
    int rl = i * 32 + trow;
    int rr = rt * 128 + rl; if (rr >= cnt) rr = cnt - 1;
    int tok = (seg == 7) ? rr : rowmap[rbase + rr];
    aptr[i] = xbf + (size_t)tok * 1024 + slot * 8;
  }
  const uint16_t* baptr[2]; const uint16_t* bbptr[2];
#pragma unroll
  for (int i = 0; i < 2; ++i) {
    int cl = i * 32 + trow;
    baptr[i] = w1e + (size_t)(n0 + cl) * 1024 + slot * 8;
    bbptr[i] = w1e + (size_t)(2048 + n0 + cl) * 1024 + slot * 8;
  }

  auto stage = [&](int buf, int kt) {
    int k0 = kt * 64;
    uint16_t* L = lds[buf];
#pragma unroll
    for (int i = 0; i < 4; ++i) gload16(&L[(i * 32 + trow) * 64 + (t & 7) * 8], aptr[i] + k0);
#pragma unroll
    for (int i = 0; i < 2; ++i) gload16(&L[8192 + (i * 32 + trow) * 64 + (t & 7) * 8], baptr[i] + k0);
#pragma unroll
    for (int i = 0; i < 2; ++i) gload16(&L[12288 + (i * 32 + trow) * 64 + (t & 7) * 8], bbptr[i] + k0);
  };

  int wr = (w >> 1) & 1, wc = w & 1;
  int l15 = lane & 15, lk = lane >> 4;
  f32x4 acca[4][2] = {};
  f32x4 accb[4][2] = {};

  stage(0, 0);
  stage(1, 1);
  for (int kt = 0; kt < 16; ++kt) {
    if (kt < 15) S_VMCNT8(); else S_VMCNT0();
    S_BAR();
    const uint16_t* L = lds[kt & 1];
#pragma unroll
    for (int g = 0; g < 2; ++g) {
      bf16x8 af[4];
#pragma unroll
      for (int m = 0; m < 4; ++m) {
        int row = wr * 64 + m * 16 + l15;
        int p = (g * 4 + lk) ^ (row & 7);
        af[m] = *reinterpret_cast<const bf16x8*>(&L[row * 64 + p * 8]);
      }
#pragma unroll
      for (int n = 0; n < 2; ++n) {
        int ca = wc * 32 + n * 16 + l15;
        int p = (g * 4 + lk) ^ (ca & 7);
        bf16x8 ba = *reinterpret_cast<const bf16x8*>(&L[8192 + ca * 64 + p * 8]);
        bf16x8 bb = *reinterpret_cast<const bf16x8*>(&L[12288 + ca * 64 + p * 8]);
#pragma unroll
        for (int m = 0; m < 4; ++m) {
          acca[m][n] = __builtin_amdgcn_mfma_f32_16x16x32_bf16(af[m], ba, acca[m][n], 0, 0, 0);
          accb[m][n] = __builtin_amdgcn_mfma_f32_16x16x32_bf16(af[m], bb, accb[m][n], 0, 0, 0);
        }
      }
    }
    S_LGKM0();
    S_BAR();
    if (kt < 14) stage(kt & 1, kt + 2);
  }

#pragma unroll
  for (int m = 0; m < 4; ++m)
#pragma unroll
    for (int n = 0; n < 2; ++n) {
      int col = n0 + wc * 32 + n * 16 + l15;
#pragma unroll
      for (int j = 0; j < 4; ++j) {
        int row = rt * 128 + wr * 64 + m * 16 + lk * 4 + j;
        if (row < cnt) {
          float a = acca[m][n][j], b = accb[m][n][j];
          float sv = b / (1.0f + __expf(-b));
          h[(size_t)(base + row) * 2048 + col] = f2bf(sv * a);
        }
      }
    }
}

// ---------------- FFN2: compact rows @ W2; shared->y, routed->yr ----------------
// BM=128, BN=128, BK=64, same dbuf scheme. grid (8 coltiles, 58 y-tiles), 256 thr.
__global__ __launch_bounds__(256, 2) void ffn2_kernel(
    const uint16_t* __restrict__ h,    // [4096][2048] bf16
    const uint16_t* __restrict__ w2t,  // [8][1024][2048] bf16 ([dout][h])
    const int* __restrict__ soff, const int* __restrict__ scnt,
    float* __restrict__ y,             // [2048][1024] f32 (shared expert, SET)
    float* __restrict__ yr)            // [2048][1024] f32 (routed compact, SET)
{
  int by = blockIdx.y;
  int seg, rt;
  if (by < 42) { seg = by / 6; rt = by % 6; } else { seg = 7; rt = by - 42; }
  int cnt = scnt[seg];
  if (rt * 128 >= cnt) return;
  int base = (seg == 7) ? 2048 : soff[seg];
  int obase = (seg == 7) ? 0 : soff[seg];
  int n0 = blockIdx.x * 128;

  __shared__ uint16_t lds[2][16384];  // As[128][64]@0, Bs[128][64]@8192

  int t = threadIdx.x, lane = t & 63, w = t >> 6;
  int trow = w * 8 + ((t >> 3) & 7);
  int slot = (t & 7) ^ (trow & 7);

  const uint16_t* w2e = w2t + (size_t)seg * (1024u * 2048u);
  const uint16_t* aptr[4]; const uint16_t* bptr[4];
#pragma unroll
  for (int i = 0; i < 4; ++i) {
    int rl = i * 32 + trow;
    int rr = rt * 128 + rl; if (rr >= cnt) rr = cnt - 1;
    aptr[i] = h + (size_t)(base + rr) * 2048 + slot * 8;
    bptr[i] = w2e + (size_t)(n0 + rl) * 2048 + slot * 8;
  }

  auto stage = [&](int buf, int kt) {
    int k0 = kt * 64;
    uint16_t* L = lds[buf];
#pragma unroll
    for (int i = 0; i < 4; ++i) gload16(&L[(i * 32 + trow) * 64 + (t & 7) * 8], aptr[i] + k0);
#pragma unroll
    for (int i = 0; i < 4; ++i) gload16(&L[8192 + (i * 32 + trow) * 64 + (t & 7) * 8], bptr[i] + k0);
  };

  int wr = (w >> 1) & 1, wc = w & 1;
  int l15 = lane & 15, lk = lane >> 4;
  f32x4 acc[4][4] = {};

  stage(0, 0);
  stage(1, 1);
  for (int kt = 0; kt < 32; ++kt) {
    if (kt < 31) S_VMCNT8(); else S_VMCNT0();
    S_BAR();
    const uint16_t* L = lds[kt & 1];
#pragma unroll
    for (int g = 0; g < 2; ++g) {
      bf16x8 af[4];
#pragma unroll
      for (int m = 0; m < 4; ++m) {
        int row = wr * 64 + m * 16 + l15;
        int p = (g * 4 + lk) ^ (row & 7);
        af[m] = *reinterpret_cast<const bf16x8*>(&L[row * 64 + p * 8]);
      }
#pragma unroll
      for (int n = 0; n < 4; ++n) {
        int cb = wc * 64 + n * 16 + l15;
        int p = (g * 4 + lk) ^ (cb & 7);
        bf16x8 bfr = *reinterpret_cast<const bf16x8*>(&L[8192 + cb * 64 + p * 8]);
#pragma unroll
        for (int m = 0; m < 4; ++m)
          acc[m][n] = __builtin_amdgcn_mfma_f32_16x16x32_bf16(af[m], bfr, acc[m][n], 0, 0, 0);
      }
    }
    S_LGKM0();
    S_BAR();
    if (kt < 30) stage(kt & 1, kt + 2);
  }

#pragma unroll
  for (int m = 0; m < 4; ++m)
#pragma unroll
    for (int n = 0; n < 4; ++n) {
      int col = n0 + wc * 64 + n * 16 + l15;
#pragma unroll
      for (int j = 0; j < 4; ++j) {
        int row = rt * 128 + wr * 64 + m * 16 + lk * 4 + j;
        if (row < cnt) {
          if (seg == 7) y[(size_t)row * 1024 + col] = acc[m][n][j];
          else          yr[(size_t)(obase + row) * 1024 + col] = acc[m][n][j];
        }
      }
    }
}

// ---------------- combine: y[m] += yr[tokrow[m]] ----------------
__global__ __launch_bounds__(256) void combine_kernel(const float* __restrict__ yr,
                                                      const int* __restrict__ tokrow,
                                                      float* __restrict__ y) {
  int m = blockIdx.x;
  int d = threadIdx.x * 4;
  int r = tokrow[m];
  float4 a = *reinterpret_cast<const float4*>(yr + (size_t)r * 1024 + d);
  float4 o = *reinterpret_cast<const float4*>(y + (size_t)m * 1024 + d);
  o.x += a.x; o.y += a.y; o.z += a.z; o.w += a.w;
  *reinterpret_cast<float4*>(y + (size_t)m * 1024 + d) = o;
}

extern "C" void kernel_launch(void* const* d_in, const int* in_sizes, int n_in,
                              void* d_out, int out_size, void* d_ws, size_t ws_size,
                              hipStream_t stream)
{
  const float* x   = (const float*)d_in[0];   // [2048][1024]
  const float* Wg  = (const float*)d_in[1];   // [1024][8]
  const float* Wl1 = (const float*)d_in[2];   // [8][1024][4096]
  const float* Wl2 = (const float*)d_in[3];   // [8][2048][1024]
  float* y = (float*)d_out;                   // [2048][1024]
  char* ws = (char*)d_ws;

  // ws layout (116 MiB + ints). yr overlays w1t (dead after ffn1).
  uint16_t* xbf = (uint16_t*)(ws);                    //  4 MiB
  uint16_t* w1t = (uint16_t*)(ws + (4ull  << 20));    // 64 MiB
  float*    yr  = (float*)   (ws + (4ull  << 20));    //  8 MiB (overlay)
  uint16_t* w2t = (uint16_t*)(ws + (68ull << 20));    // 32 MiB
  uint16_t* h   = (uint16_t*)(ws + (100ull << 20));   // 16 MiB
  int* idx    = (int*)(ws + (116ull << 20));
  int* perm   = idx + 2048;
  int* tokrow = perm + 2048;
  int* cnt    = tokrow + 2048;
  int* soff   = cnt + 8;
  int* scnt   = soff + 8;
  int* rowmap = scnt + 8;  // 2048 ints (routed only)

  hipMemsetAsync(cnt, 0, 8 * sizeof(int), stream);
  gate_kernel<<<512, 256, 0, stream>>>(x, Wg, xbf, idx, perm, cnt);
  compact_kernel<<<1, 256, 0, stream>>>(idx, perm, cnt, soff, scnt, rowmap, tokrow);
  tcvt_kernel<<<dim3(64, 16, 8), 256, 0, stream>>>(Wl1, w1t, 1024, 4096);
  tcvt_kernel<<<dim3(16, 32, 8), 256, 0, stream>>>(Wl2, w2t, 2048, 1024);
  ffn1_kernel<<<dim3(32, 58), 256, 0, stream>>>(xbf, w1t, soff, scnt, rowmap, h);
  ffn2_kernel<<<dim3(8, 58), 256, 0, stream>>>(h, w2t, soff, scnt, y, yr);
  combine_kernel<<<2048, 256, 0, stream>>>(yr, tokrow, y);
}

// Round 3
// 158.001 us; speedup vs baseline: 1.7882x; 1.1815x over previous
//
#include <hip/hip_runtime.h>
#include <stdint.h>

// MoE: D=1024, N=8 experts, top-1 routed (experts 0..6) + shared expert 7,
// gates are exactly 1.0. M=2048 tokens, H=2048.

typedef __bf16 bf16x8 __attribute__((ext_vector_type(8)));
typedef float f32x4 __attribute__((ext_vector_type(4)));

typedef __attribute__((address_space(1))) const void gvoid_t;
typedef __attribute__((address_space(3))) void lvoid_t;

__device__ __forceinline__ void gload16(void* lds, const void* g) {
  __builtin_amdgcn_global_load_lds((gvoid_t*)g, (lvoid_t*)lds, 16, 0, 0);
}

__device__ __forceinline__ uint16_t f2bf(float f) {
  union { float f; uint32_t u; } v; v.f = f;
  uint32_t u = v.u + 0x7fffu + ((v.u >> 16) & 1u);  // RNE
  return (uint16_t)(u >> 16);
}

#define S_VMCNT8() asm volatile("s_waitcnt vmcnt(8)" ::: "memory")
#define S_VMCNT0() asm volatile("s_waitcnt vmcnt(0)" ::: "memory")
#define S_LGKM0()  asm volatile("s_waitcnt lgkmcnt(0)" ::: "memory")
#define S_BAR()    __builtin_amdgcn_s_barrier()

// ------- merged transpose+convert for W1 and W2: [E][R][C] f32 -> [E][C][R] bf16 -------
__global__ __launch_bounds__(256) void tcvt_all(const float* __restrict__ W1,
                                                const float* __restrict__ W2,
                                                uint16_t* __restrict__ w1t,
                                                uint16_t* __restrict__ w2t) {
  __shared__ uint16_t tile[64][80];
  int b = blockIdx.x;
  const float* s; uint16_t* d; int R, C, c0, r0;
  if (b < 8192) {                    // W1: per expert grid 64 x 16
    int e = b >> 10, r = b & 1023;
    R = 1024; C = 4096;
    c0 = (r & 63) * 64; r0 = (r >> 6) * 64;
    s = W1 + (size_t)e * R * C;
    d = w1t + (size_t)e * R * C;
  } else {                           // W2: per expert grid 16 x 32
    int bb = b - 8192;
    int e = bb >> 9, r = bb & 511;
    R = 2048; C = 1024;
    c0 = (r & 15) * 64; r0 = (r >> 4) * 64;
    s = W2 + (size_t)e * R * C;
    d = w2t + (size_t)e * R * C;
  }
  int t = threadIdx.x;
  int rl = t >> 4, cq = t & 15;
  for (int it = 0; it < 4; ++it) {
    int r = rl + it * 16;
    float4 v = *reinterpret_cast<const float4*>(s + (size_t)(r0 + r) * C + c0 + cq * 4);
    tile[cq * 4 + 0][r] = f2bf(v.x);
    tile[cq * 4 + 1][r] = f2bf(v.y);
    tile[cq * 4 + 2][r] = f2bf(v.z);
    tile[cq * 4 + 3][r] = f2bf(v.w);
  }
  __syncthreads();
  for (int it = 0; it < 2; ++it) {
    int slot = t + it * 256;
    int cl = slot >> 3, rg = slot & 7;
    uint4 v = *reinterpret_cast<const uint4*>(&tile[cl][rg * 8]);
    *reinterpret_cast<uint4*>(d + (size_t)(c0 + cl) * R + r0 + rg * 8) = v;
  }
}

// ---------------- gating + x->bf16 convert fused (no atomics) ----------------
__global__ __launch_bounds__(256) void gate_kernel(const float* __restrict__ x,
                                                   const float* __restrict__ Wg,
                                                   uint16_t* __restrict__ xbf,
                                                   int* __restrict__ idx) {
  int wid = threadIdx.x >> 6, lane = threadIdx.x & 63;
  int m = blockIdx.x * 4 + wid;
  const float* xr = x + (size_t)m * 1024;
  uint16_t* xbr = xbf + (size_t)m * 1024;
  float acc[8] = {0.f, 0.f, 0.f, 0.f, 0.f, 0.f, 0.f, 0.f};
  for (int it = 0; it < 4; ++it) {
    int dbase = it * 256 + lane * 4;
    float4 xv = *reinterpret_cast<const float4*>(xr + dbase);
    ushort4 o;
    o.x = f2bf(xv.x); o.y = f2bf(xv.y); o.z = f2bf(xv.z); o.w = f2bf(xv.w);
    *reinterpret_cast<ushort4*>(xbr + dbase) = o;
    const float* xp = reinterpret_cast<const float*>(&xv);
    for (int dd = 0; dd < 4; ++dd) {
      float xs = xp[dd];
      float4 w0 = *reinterpret_cast<const float4*>(Wg + (size_t)(dbase + dd) * 8);
      float4 w1 = *reinterpret_cast<const float4*>(Wg + (size_t)(dbase + dd) * 8 + 4);
      acc[0] += xs * w0.x; acc[1] += xs * w0.y; acc[2] += xs * w0.z; acc[3] += xs * w0.w;
      acc[4] += xs * w1.x; acc[5] += xs * w1.y; acc[6] += xs * w1.z; acc[7] += xs * w1.w;
    }
  }
  for (int j = 0; j < 7; ++j)
    for (int off = 32; off; off >>= 1)
      acc[j] += __shfl_xor(acc[j], off);
  if (lane == 0) {
    int best = 0; float bv = acc[0];
    for (int j = 1; j < 7; ++j) if (acc[j] > bv) { bv = acc[j]; best = j; }
    idx[m] = best;
  }
}

// -------- single-block stable counting sort: offsets, rowmap, tokrow --------
__global__ __launch_bounds__(256) void compact_kernel(const int* __restrict__ idx,
                                                      int* __restrict__ soff,
                                                      int* __restrict__ scnt,
                                                      int* __restrict__ rowmap,
                                                      int* __restrict__ tokrow) {
  __shared__ int hist[256][7];
  __shared__ int cnts[7];
  __shared__ int off[7];
  int t = threadIdx.x;
  int e8[8];
  int lh[7] = {0, 0, 0, 0, 0, 0, 0};
#pragma unroll
  for (int i = 0; i < 8; ++i) { int e = idx[t * 8 + i]; e8[i] = e; lh[e]++; }
#pragma unroll
  for (int e = 0; e < 7; ++e) hist[t][e] = lh[e];
  __syncthreads();
  if (t < 7) {
    int run = 0;
    for (int i = 0; i < 256; ++i) { int v = hist[i][t]; hist[i][t] = run; run += v; }
    cnts[t] = run;
  }
  __syncthreads();
  if (t == 0) {
    int run = 0;
    for (int e = 0; e < 7; ++e) { off[e] = run; soff[e] = run; scnt[e] = cnts[e]; run += cnts[e]; }
    soff[7] = 0; scnt[7] = 2048;
  }
  __syncthreads();
  int pos[7];
#pragma unroll
  for (int e = 0; e < 7; ++e) pos[e] = off[e] + hist[t][e];
#pragma unroll
  for (int i = 0; i < 8; ++i) {
    int m = t * 8 + i, e = e8[i];
    int r = pos[e]++;
    rowmap[r] = m;
    tokrow[m] = r;
  }
}

// ---------------- FFN1: h = silu(x@W1_b) * (x@W1_a) ----------------
// BM=128 rows, 64 a-cols + 64 b-cols, BK=64, dbuf counted-vmcnt, swizzled LDS.
__global__ __launch_bounds__(256, 2) void ffn1_kernel(
    const uint16_t* __restrict__ xbf,   // [2048][1024] bf16
    const uint16_t* __restrict__ w1t,   // [8][4096][1024] bf16 ([n][d])
    const int* __restrict__ soff, const int* __restrict__ scnt,
    const int* __restrict__ rowmap,
    uint16_t* __restrict__ h)           // [4096 compact rows][2048] bf16
{
  int by = blockIdx.y;
  int seg, rt;
  if (by < 42) { seg = by / 6; rt = by % 6; } else { seg = 7; rt = by - 42; }
  int cnt = scnt[seg];
  if (rt * 128 >= cnt) return;
  int base = (seg == 7) ? 2048 : soff[seg];
  int rbase = (seg == 7) ? 0 : soff[seg];
  int n0 = blockIdx.x * 64;

  __shared__ uint16_t lds[2][16384];  // As[128][64]@0, Ba[64][64]@8192, Bb@12288

  int t = threadIdx.x, lane = t & 63, w = t >> 6;
  int trow = w * 8 + ((t >> 3) & 7);
  int slot = (t & 7) ^ (trow & 7);

  const uint16_t* w1e = w1t + (size_t)seg * (4096u * 1024u);
  const uint16_t* aptr[4];
#pragma unroll
  for (int i = 0; i < 4; ++i) {
    int rl = i * 32 + trow;
    int rr = rt * 128 + rl; if (rr >= cnt) rr = cnt - 1;
    int tok = (seg == 7) ? rr : rowmap[rbase + rr];
    aptr[i] = xbf + (size_t)tok * 1024 + slot * 8;
  }
  const uint16_t* baptr[2]; const uint16_t* bbptr[2];
#pragma unroll
  for (int i = 0; i < 2; ++i) {
    int cl = i * 32 + trow;
    baptr[i] = w1e + (size_t)(n0 + cl) * 1024 + slot * 8;
    bbptr[i] = w1e + (size_t)(2048 + n0 + cl) * 1024 + slot * 8;
  }

  auto stage = [&](int buf, int kt) {
    int k0 = kt * 64;
    uint16_t* L = lds[buf];
#pragma unroll
    for (int i = 0; i < 4; ++i) gload16(&L[(i * 32 + trow) * 64 + (t & 7) * 8], aptr[i] + k0);
#pragma unroll
    for (int i = 0; i < 2; ++i) gload16(&L[8192 + (i * 32 + trow) * 64 + (t & 7) * 8], baptr[i] + k0);
#pragma unroll
    for (int i = 0; i < 2; ++i) gload16(&L[12288 + (i * 32 + trow) * 64 + (t & 7) * 8], bbptr[i] + k0);
  };

  int wr = (w >> 1) & 1, wc = w & 1;
  int l15 = lane & 15, lk = lane >> 4;
  f32x4 acca[4][2] = {};
  f32x4 accb[4][2] = {};

  stage(0, 0);
  stage(1, 1);
  for (int kt = 0; kt < 16; ++kt) {
    if (kt < 15) S_VMCNT8(); else S_VMCNT0();
    S_BAR();
    const uint16_t* L = lds[kt & 1];
#pragma unroll
    for (int g = 0; g < 2; ++g) {
      __builtin_amdgcn_s_setprio(1);
      bf16x8 af[4];
#pragma unroll
      for (int m = 0; m < 4; ++m) {
        int row = wr * 64 + m * 16 + l15;
        int p = (g * 4 + lk) ^ (row & 7);
        af[m] = *reinterpret_cast<const bf16x8*>(&L[row * 64 + p * 8]);
      }
#pragma unroll
      for (int n = 0; n < 2; ++n) {
        int ca = wc * 32 + n * 16 + l15;
        int p = (g * 4 + lk) ^ (ca & 7);
        bf16x8 ba = *reinterpret_cast<const bf16x8*>(&L[8192 + ca * 64 + p * 8]);
        bf16x8 bb = *reinterpret_cast<const bf16x8*>(&L[12288 + ca * 64 + p * 8]);
#pragma unroll
        for (int m = 0; m < 4; ++m) {
          acca[m][n] = __builtin_amdgcn_mfma_f32_16x16x32_bf16(af[m], ba, acca[m][n], 0, 0, 0);
          accb[m][n] = __builtin_amdgcn_mfma_f32_16x16x32_bf16(af[m], bb, accb[m][n], 0, 0, 0);
        }
      }
      __builtin_amdgcn_s_setprio(0);
    }
    S_LGKM0();
    S_BAR();
    if (kt < 14) stage(kt & 1, kt + 2);
  }

#pragma unroll
  for (int m = 0; m < 4; ++m)
#pragma unroll
    for (int n = 0; n < 2; ++n) {
      int col = n0 + wc * 32 + n * 16 + l15;
#pragma unroll
      for (int j = 0; j < 4; ++j) {
        int row = rt * 128 + wr * 64 + m * 16 + lk * 4 + j;
        if (row < cnt) {
          float a = acca[m][n][j], b = accb[m][n][j];
          float sv = b / (1.0f + __expf(-b));
          h[(size_t)(base + row) * 2048 + col] = f2bf(sv * a);
        }
      }
    }
}

// ---------------- FFN2: compact rows @ W2; shared->y, routed->yr ----------------
__global__ __launch_bounds__(256, 2) void ffn2_kernel(
    const uint16_t* __restrict__ h,    // [4096][2048] bf16
    const uint16_t* __restrict__ w2t,  // [8][1024][2048] bf16 ([dout][h])
    const int* __restrict__ soff, const int* __restrict__ scnt,
    float* __restrict__ y,             // [2048][1024] f32 (shared expert, SET)
    float* __restrict__ yr)            // [2048][1024] f32 (routed compact, SET)
{
  int by = blockIdx.y;
  int seg, rt;
  if (by < 42) { seg = by / 6; rt = by % 6; } else { seg = 7; rt = by - 42; }
  int cnt = scnt[seg];
  if (rt * 128 >= cnt) return;
  int base = (seg == 7) ? 2048 : soff[seg];
  int obase = (seg == 7) ? 0 : soff[seg];
  int n0 = blockIdx.x * 128;

  __shared__ uint16_t lds[2][16384];  // As[128][64]@0, Bs[128][64]@8192

  int t = threadIdx.x, lane = t & 63, w = t >> 6;
  int trow = w * 8 + ((t >> 3) & 7);
  int slot = (t & 7) ^ (trow & 7);

  const uint16_t* w2e = w2t + (size_t)seg * (1024u * 2048u);
  const uint16_t* aptr[4]; const uint16_t* bptr[4];
#pragma unroll
  for (int i = 0; i < 4; ++i) {
    int rl = i * 32 + trow;
    int rr = rt * 128 + rl; if (rr >= cnt) rr = cnt - 1;
    aptr[i] = h + (size_t)(base + rr) * 2048 + slot * 8;
    bptr[i] = w2e + (size_t)(n0 + rl) * 2048 + slot * 8;
  }

  auto stage = [&](int buf, int kt) {
    int k0 = kt * 64;
    uint16_t* L = lds[buf];
#pragma unroll
    for (int i = 0; i < 4; ++i) gload16(&L[(i * 32 + trow) * 64 + (t & 7) * 8], aptr[i] + k0);
#pragma unroll
    for (int i = 0; i < 4; ++i) gload16(&L[8192 + (i * 32 + trow) * 64 + (t & 7) * 8], bptr[i] + k0);
  };

  int wr = (w >> 1) & 1, wc = w & 1;
  int l15 = lane & 15, lk = lane >> 4;
  f32x4 acc[4][4] = {};

  stage(0, 0);
  stage(1, 1);
  for (int kt = 0; kt < 32; ++kt) {
    if (kt < 31) S_VMCNT8(); else S_VMCNT0();
    S_BAR();
    const uint16_t* L = lds[kt & 1];
#pragma unroll
    for (int g = 0; g < 2; ++g) {
      __builtin_amdgcn_s_setprio(1);
      bf16x8 af[4];
#pragma unroll
      for (int m = 0; m < 4; ++m) {
        int row = wr * 64 + m * 16 + l15;
        int p = (g * 4 + lk) ^ (row & 7);
        af[m] = *reinterpret_cast<const bf16x8*>(&L[row * 64 + p * 8]);
      }
#pragma unroll
      for (int n = 0; n < 4; ++n) {
        int cb = wc * 64 + n * 16 + l15;
        int p = (g * 4 + lk) ^ (cb & 7);
        bf16x8 bfr = *reinterpret_cast<const bf16x8*>(&L[8192 + cb * 64 + p * 8]);
#pragma unroll
        for (int m = 0; m < 4; ++m)
          acc[m][n] = __builtin_amdgcn_mfma_f32_16x16x32_bf16(af[m], bfr, acc[m][n], 0, 0, 0);
      }
      __builtin_amdgcn_s_setprio(0);
    }
    S_LGKM0();
    S_BAR();
    if (kt < 30) stage(kt & 1, kt + 2);
  }

#pragma unroll
  for (int m = 0; m < 4; ++m)
#pragma unroll
    for (int n = 0; n < 4; ++n) {
      int col = n0 + wc * 64 + n * 16 + l15;
#pragma unroll
      for (int j = 0; j < 4; ++j) {
        int row = rt * 128 + wr * 64 + m * 16 + lk * 4 + j;
        if (row < cnt) {
          if (seg == 7) y[(size_t)row * 1024 + col] = acc[m][n][j];
          else          yr[(size_t)(obase + row) * 1024 + col] = acc[m][n][j];
        }
      }
    }
}

// ---------------- combine: y[m] += yr[tokrow[m]] ----------------
__global__ __launch_bounds__(256) void combine_kernel(const float* __restrict__ yr,
                                                      const int* __restrict__ tokrow,
                                                      float* __restrict__ y) {
  int m = blockIdx.x;
  int d = threadIdx.x * 4;
  int r = tokrow[m];
  float4 a = *reinterpret_cast<const float4*>(yr + (size_t)r * 1024 + d);
  float4 o = *reinterpret_cast<const float4*>(y + (size_t)m * 1024 + d);
  o.x += a.x; o.y += a.y; o.z += a.z; o.w += a.w;
  *reinterpret_cast<float4*>(y + (size_t)m * 1024 + d) = o;
}

extern "C" void kernel_launch(void* const* d_in, const int* in_sizes, int n_in,
                              void* d_out, int out_size, void* d_ws, size_t ws_size,
                              hipStream_t stream)
{
  const float* x   = (const float*)d_in[0];   // [2048][1024]
  const float* Wg  = (const float*)d_in[1];   // [1024][8]
  const float* Wl1 = (const float*)d_in[2];   // [8][1024][4096]
  const float* Wl2 = (const float*)d_in[3];   // [8][2048][1024]
  float* y = (float*)d_out;                   // [2048][1024]
  char* ws = (char*)d_ws;

  // ws layout. yr overlays w1t (dead after ffn1).
  uint16_t* xbf = (uint16_t*)(ws);                    //  4 MiB
  uint16_t* w1t = (uint16_t*)(ws + (4ull  << 20));    // 64 MiB
  float*    yr  = (float*)   (ws + (4ull  << 20));    //  8 MiB (overlay)
  uint16_t* w2t = (uint16_t*)(ws + (68ull << 20));    // 32 MiB
  uint16_t* h   = (uint16_t*)(ws + (100ull << 20));   // 16 MiB
  int* idx    = (int*)(ws + (116ull << 20));
  int* tokrow = idx + 2048;
  int* soff   = tokrow + 2048;
  int* scnt   = soff + 8;
  int* rowmap = scnt + 8;  // 2048 ints

  gate_kernel<<<512, 256, 0, stream>>>(x, Wg, xbf, idx);
  compact_kernel<<<1, 256, 0, stream>>>(idx, soff, scnt, rowmap, tokrow);
  tcvt_all<<<12288, 256, 0, stream>>>(Wl1, Wl2, w1t, w2t);
  ffn1_kernel<<<dim3(32, 58), 256, 0, stream>>>(xbf, w1t, soff, scnt, rowmap, h);
  ffn2_kernel<<<dim3(8, 58), 256, 0, stream>>>(h, w2t, soff, scnt, y, yr);
  combine_kernel<<<2048, 256, 0, stream>>>(yr, tokrow, y);
}